// Round 15
// baseline (486.490 us; speedup 1.0000x reference)
//
#include <hip/hip_runtime.h>

#define B_ 2
#define N_ 1024
#define C_ 1024
#define H_ 16
#define HD_ 64
#define KPAD 36   // u32 per LDS row (144B stride): 16B-aligned b128 reads
#define KPADL 40  // u16 per LDS row (80B stride): 16B-aligned b128 reads

typedef short short8 __attribute__((ext_vector_type(8)));
typedef float f32x4 __attribute__((ext_vector_type(4)));
typedef unsigned short ushort_t;

union U16 {
  uint4 q;
  unsigned u[4];
  short8 s;
};

// ---------- wave-wide (64-lane) helpers ----------
__device__ __forceinline__ float wsumf(float x) {
#pragma unroll
  for (int off = 32; off; off >>= 1) x += __shfl_xor(x, off, 64);
  return x;
}
__device__ __forceinline__ unsigned orderu(float f) {
  unsigned b = __float_as_uint(f);
  return (b & 0x80000000u) ? ~b : (b | 0x80000000u);
}
__device__ __forceinline__ float iorderu(unsigned x) {
  unsigned b = (x & 0x80000000u) ? (x & 0x7FFFFFFFu) : ~x;
  return __uint_as_float(b);
}

// 2-term split f32 -> packed u32: hi bf16 low16, lo bf16 high16 (RTNE)
__device__ __forceinline__ unsigned splitf2(float f) {
  unsigned u = __float_as_uint(f);
  unsigned t = (u + 0x7fffu + ((u >> 16) & 1u)) & 0xffff0000u;
  float r = f - __uint_as_float(t);  // exact
  unsigned v = __float_as_uint(r);
  unsigned tv = v + 0x7fffu + ((v >> 16) & 1u);
  return (t >> 16) | (tv & 0xffff0000u);
}
// 3-term split: hm = hi|mid packed u32, lo = third bf16 term
__device__ __forceinline__ void splitf3(float f, unsigned& hm,
                                        unsigned short& lo) {
  unsigned u = __float_as_uint(f);
  unsigned t = (u + 0x7fffu + ((u >> 16) & 1u)) & 0xffff0000u;
  float r1 = f - __uint_as_float(t);  // exact
  unsigned v = __float_as_uint(r1);
  unsigned tv = (v + 0x7fffu + ((v >> 16) & 1u)) & 0xffff0000u;
  float r2 = r1 - __uint_as_float(tv);  // exact
  unsigned w = __float_as_uint(r2);
  unsigned tw = w + 0x7fffu + ((w >> 16) & 1u);
  hm = (t >> 16) | tv;
  lo = (unsigned short)(tw >> 16);
}

__device__ __forceinline__ void unpack_hm(const unsigned* p, short8& h,
                                          short8& l) {
  const uint4 X = *(const uint4*)p;
  const uint4 Y = *(const uint4*)(p + 4);
  U16 Hh, Ll;
  Hh.u[0] = (X.x & 0xffffu) | (X.y << 16);
  Hh.u[1] = (X.z & 0xffffu) | (X.w << 16);
  Hh.u[2] = (Y.x & 0xffffu) | (Y.y << 16);
  Hh.u[3] = (Y.z & 0xffffu) | (Y.w << 16);
  Ll.u[0] = (X.x >> 16) | (X.y & 0xffff0000u);
  Ll.u[1] = (X.z >> 16) | (X.w & 0xffff0000u);
  Ll.u[2] = (Y.x >> 16) | (Y.y & 0xffff0000u);
  Ll.u[3] = (Y.z >> 16) | (Y.w & 0xffff0000u);
  h = Hh.s;
  l = Ll.s;
}

// ---------- 3-term split MFMA core, 128x64 tile, BK=32, 4 waves (2x2) ----------
__device__ __forceinline__ void mfma_core6(
    const float* __restrict__ A, const float* __restrict__ Bm, int lda,
    int ldb, int m0, int n0, unsigned* a_hm, unsigned* b_hm,
    unsigned short* a_lo, unsigned short* b_lo, f32x4 acc[4][2]) {
  const int tid = threadIdx.x;
  const int lane = tid & 63;
  const int wro = ((tid >> 7) & 1) * 64;
  const int wco = ((tid >> 6) & 1) * 32;
  const int a_k4 = (tid & 7) * 4, a_m = tid >> 3;
  const int b_k = tid >> 4;
  const int b_j4 = (tid & 15) * 4;
  const int fr = lane & 15, fk = (lane >> 4) * 8;

  float4 aR[4], bR[2];
#pragma unroll
  for (int j = 0; j < 4; ++j)
    aR[j] = *(const float4*)(A + (size_t)(m0 + a_m + 32 * j) * lda + a_k4);
  bR[0] = *(const float4*)(Bm + (size_t)b_k * ldb + n0 + b_j4);
  bR[1] = *(const float4*)(Bm + (size_t)(b_k + 16) * ldb + n0 + b_j4);

  for (int kt = 0; kt < 32; ++kt) {
    __syncthreads();
#pragma unroll
    for (int j = 0; j < 4; ++j) {
      uint4 w;
      ushort4 l;
      splitf3(aR[j].x, w.x, l.x);
      splitf3(aR[j].y, w.y, l.y);
      splitf3(aR[j].z, w.z, l.z);
      splitf3(aR[j].w, w.w, l.w);
      *(uint4*)(a_hm + (a_m + 32 * j) * KPAD + a_k4) = w;
      *(ushort4*)(a_lo + (a_m + 32 * j) * KPADL + a_k4) = l;
    }
    {
      unsigned hm;
      unsigned short lo;
      splitf3(bR[0].x, hm, lo);
      b_hm[(b_j4 + 0) * KPAD + b_k] = hm;
      b_lo[(b_j4 + 0) * KPADL + b_k] = lo;
      splitf3(bR[0].y, hm, lo);
      b_hm[(b_j4 + 1) * KPAD + b_k] = hm;
      b_lo[(b_j4 + 1) * KPADL + b_k] = lo;
      splitf3(bR[0].z, hm, lo);
      b_hm[(b_j4 + 2) * KPAD + b_k] = hm;
      b_lo[(b_j4 + 2) * KPADL + b_k] = lo;
      splitf3(bR[0].w, hm, lo);
      b_hm[(b_j4 + 3) * KPAD + b_k] = hm;
      b_lo[(b_j4 + 3) * KPADL + b_k] = lo;
      splitf3(bR[1].x, hm, lo);
      b_hm[(b_j4 + 0) * KPAD + b_k + 16] = hm;
      b_lo[(b_j4 + 0) * KPADL + b_k + 16] = lo;
      splitf3(bR[1].y, hm, lo);
      b_hm[(b_j4 + 1) * KPAD + b_k + 16] = hm;
      b_lo[(b_j4 + 1) * KPADL + b_k + 16] = lo;
      splitf3(bR[1].z, hm, lo);
      b_hm[(b_j4 + 2) * KPAD + b_k + 16] = hm;
      b_lo[(b_j4 + 2) * KPADL + b_k + 16] = lo;
      splitf3(bR[1].w, hm, lo);
      b_hm[(b_j4 + 3) * KPAD + b_k + 16] = hm;
      b_lo[(b_j4 + 3) * KPADL + b_k + 16] = lo;
    }
    __syncthreads();
    if (kt + 1 < 32) {
      const int kb = (kt + 1) * 32;
#pragma unroll
      for (int j = 0; j < 4; ++j)
        aR[j] =
            *(const float4*)(A + (size_t)(m0 + a_m + 32 * j) * lda + kb + a_k4);
      bR[0] = *(const float4*)(Bm + (size_t)(kb + b_k) * ldb + n0 + b_j4);
      bR[1] = *(const float4*)(Bm + (size_t)(kb + b_k + 16) * ldb + n0 + b_j4);
    }
    short8 ah[4], am[4], al[4];
#pragma unroll
    for (int rt = 0; rt < 4; ++rt) {
      const int row = wro + rt * 16 + fr;
      unpack_hm(a_hm + row * KPAD + fk, ah[rt], am[rt]);
      U16 L;
      L.q = *(const uint4*)(a_lo + row * KPADL + fk);
      al[rt] = L.s;
    }
#pragma unroll
    for (int ct = 0; ct < 2; ++ct) {
      const int row = wco + ct * 16 + fr;
      short8 bh, bm, bl;
      unpack_hm(b_hm + row * KPAD + fk, bh, bm);
      U16 L;
      L.q = *(const uint4*)(b_lo + row * KPADL + fk);
      bl = L.s;
#pragma unroll
      for (int rt = 0; rt < 4; ++rt) {
        f32x4 c = acc[rt][ct];
        c = __builtin_amdgcn_mfma_f32_16x16x32_bf16(ah[rt], bl, c, 0, 0, 0);
        c = __builtin_amdgcn_mfma_f32_16x16x32_bf16(al[rt], bh, c, 0, 0, 0);
        c = __builtin_amdgcn_mfma_f32_16x16x32_bf16(am[rt], bm, c, 0, 0, 0);
        c = __builtin_amdgcn_mfma_f32_16x16x32_bf16(ah[rt], bm, c, 0, 0, 0);
        c = __builtin_amdgcn_mfma_f32_16x16x32_bf16(am[rt], bh, c, 0, 0, 0);
        c = __builtin_amdgcn_mfma_f32_16x16x32_bf16(ah[rt], bh, c, 0, 0, 0);
        acc[rt][ct] = c;
      }
    }
  }
}

// ---------- 2-term split MFMA core, 128x64 tile (v / out-proj) ----------
__device__ __forceinline__ void mfma_core3(const float* __restrict__ A,
                                           const float* __restrict__ Bm,
                                           int lda, int ldb, int m0, int n0,
                                           unsigned* a_hm, unsigned* b_hm,
                                           f32x4 acc[4][2]) {
  const int tid = threadIdx.x;
  const int lane = tid & 63;
  const int wro = ((tid >> 7) & 1) * 64;
  const int wco = ((tid >> 6) & 1) * 32;
  const int a_k4 = (tid & 7) * 4, a_m = tid >> 3;
  const int b_k = tid >> 4;
  const int b_j4 = (tid & 15) * 4;
  const int fr = lane & 15, fk = (lane >> 4) * 8;

  float4 aR[4], bR[2];
#pragma unroll
  for (int j = 0; j < 4; ++j)
    aR[j] = *(const float4*)(A + (size_t)(m0 + a_m + 32 * j) * lda + a_k4);
  bR[0] = *(const float4*)(Bm + (size_t)b_k * ldb + n0 + b_j4);
  bR[1] = *(const float4*)(Bm + (size_t)(b_k + 16) * ldb + n0 + b_j4);

  for (int kt = 0; kt < 32; ++kt) {
    __syncthreads();
#pragma unroll
    for (int j = 0; j < 4; ++j) {
      uint4 w;
      w.x = splitf2(aR[j].x);
      w.y = splitf2(aR[j].y);
      w.z = splitf2(aR[j].z);
      w.w = splitf2(aR[j].w);
      *(uint4*)(a_hm + (a_m + 32 * j) * KPAD + a_k4) = w;
    }
    {
      b_hm[(b_j4 + 0) * KPAD + b_k] = splitf2(bR[0].x);
      b_hm[(b_j4 + 1) * KPAD + b_k] = splitf2(bR[0].y);
      b_hm[(b_j4 + 2) * KPAD + b_k] = splitf2(bR[0].z);
      b_hm[(b_j4 + 3) * KPAD + b_k] = splitf2(bR[0].w);
      b_hm[(b_j4 + 0) * KPAD + b_k + 16] = splitf2(bR[1].x);
      b_hm[(b_j4 + 1) * KPAD + b_k + 16] = splitf2(bR[1].y);
      b_hm[(b_j4 + 2) * KPAD + b_k + 16] = splitf2(bR[1].z);
      b_hm[(b_j4 + 3) * KPAD + b_k + 16] = splitf2(bR[1].w);
    }
    __syncthreads();
    if (kt + 1 < 32) {
      const int kb = (kt + 1) * 32;
#pragma unroll
      for (int j = 0; j < 4; ++j)
        aR[j] =
            *(const float4*)(A + (size_t)(m0 + a_m + 32 * j) * lda + kb + a_k4);
      bR[0] = *(const float4*)(Bm + (size_t)(kb + b_k) * ldb + n0 + b_j4);
      bR[1] = *(const float4*)(Bm + (size_t)(kb + b_k + 16) * ldb + n0 + b_j4);
    }
    short8 ah[4], al[4];
#pragma unroll
    for (int rt = 0; rt < 4; ++rt)
      unpack_hm(a_hm + (wro + rt * 16 + fr) * KPAD + fk, ah[rt], al[rt]);
#pragma unroll
    for (int ct = 0; ct < 2; ++ct) {
      short8 bh, bl;
      unpack_hm(b_hm + (wco + ct * 16 + fr) * KPAD + fk, bh, bl);
#pragma unroll
      for (int rt = 0; rt < 4; ++rt) {
        f32x4 c = acc[rt][ct];
        c = __builtin_amdgcn_mfma_f32_16x16x32_bf16(ah[rt], bl, c, 0, 0, 0);
        c = __builtin_amdgcn_mfma_f32_16x16x32_bf16(al[rt], bh, c, 0, 0, 0);
        c = __builtin_amdgcn_mfma_f32_16x16x32_bf16(ah[rt], bh, c, 0, 0, 0);
        acc[rt][ct] = c;
      }
    }
  }
}

// ---------- fused front: qk tiles write q/k 3-term bf16 planes [bh][n][d];
//            v tiles write f32 v; factor groups ----------
__global__ __launch_bounds__(256) void front_kernel(
    const float* __restrict__ x, const float* __restrict__ w,
    const float* __restrict__ alpha_p, const float* __restrict__ beta_p,
    ushort_t* __restrict__ qh, ushort_t* __restrict__ qm,
    ushort_t* __restrict__ ql, ushort_t* __restrict__ kh,
    ushort_t* __restrict__ km, ushort_t* __restrict__ kl,
    float* __restrict__ v, float* __restrict__ fac) {
  __shared__ unsigned a_hm[128 * KPAD];
  __shared__ unsigned b_hm[64 * KPAD];
  __shared__ unsigned short a_lo[128 * KPADL];
  __shared__ unsigned short b_lo[64 * KPADL];

  const int bid = blockIdx.x;
  const int lane = threadIdx.x & 63;

  if (bid < 512) {  // ---- qk tile ----
    f32x4 acc[4][2];
#pragma unroll
    for (int i = 0; i < 4; ++i)
#pragma unroll
      for (int j = 0; j < 2; ++j) acc[i][j] = (f32x4){0.f, 0.f, 0.f, 0.f};
    const int m0 = (bid >> 5) * 128, n0 = (bid & 31) * 64;
    mfma_core6(x, w, C_, 3 * C_, m0, n0, a_hm, b_hm, a_lo, b_lo, acc);

    const int wro = ((threadIdx.x >> 7) & 1) * 64;
    const int wco = ((threadIdx.x >> 6) & 1) * 32;
    const int rbase = (lane >> 4) * 4, cc = lane & 15;
#pragma unroll
    for (int rt = 0; rt < 4; ++rt) {
      const int m = m0 + wro + rt * 16 + rbase;
      const int bb2 = m >> 10, nn = m & 1023;
#pragma unroll
      for (int ct = 0; ct < 2; ++ct) {
        const int j = n0 + wco + ct * 16 + cc;
        const int sel = j >> 10, hh = (j >> 6) & 15, d0 = j & 63;
        const f32x4 c = acc[rt][ct];
        ushort_t* ph = sel ? kh : qh;
        ushort_t* pmid = sel ? km : qm;
        ushort_t* plo = sel ? kl : ql;
        const size_t bse = (((size_t)(bb2 * 16 + hh) << 10) + nn) * 64 + d0;
#pragma unroll
        for (int r = 0; r < 4; ++r) {
          unsigned hmv;
          unsigned short lov;
          splitf3(c[r], hmv, lov);
          ph[bse + 64 * r] = (ushort_t)(hmv & 0xffffu);
          pmid[bse + 64 * r] = (ushort_t)(hmv >> 16);
          plo[bse + 64 * r] = lov;
        }
      }
    }
  } else if (bid < 768) {  // ---- v tile ----
    f32x4 acc[4][2];
#pragma unroll
    for (int i = 0; i < 4; ++i)
#pragma unroll
      for (int j = 0; j < 2; ++j) acc[i][j] = (f32x4){0.f, 0.f, 0.f, 0.f};
    const int vb = bid - 512;
    const int m0 = (vb >> 4) * 128, n0 = 2048 + (vb & 15) * 64;
    mfma_core3(x, w, C_, 3 * C_, m0, n0, a_hm, b_hm, acc);

    const int wro = ((threadIdx.x >> 7) & 1) * 64;
    const int wco = ((threadIdx.x >> 6) & 1) * 32;
    const int rbase = (lane >> 4) * 4, cc = lane & 15;
#pragma unroll
    for (int rt = 0; rt < 4; ++rt) {
      const int m = m0 + wro + rt * 16 + rbase;
      const int bb = m >> 10, nn = m & 1023;
#pragma unroll
      for (int ct = 0; ct < 2; ++ct) {
        const int jv = (n0 - 2048) + wco + ct * 16 + cc;
        const int hh = (jv >> 6) & 15, d0 = jv & 63;
        const f32x4 c = acc[rt][ct];
        float* dst = v + (((size_t)(bb * 16 + hh) << 10) + nn) * HD_ + d0;
        dst[0] = c[0];
        dst[HD_] = c[1];
        dst[2 * HD_] = c[2];
        dst[3 * HD_] = c[3];
      }
    }
  } else {  // ---- NKAT factor: 4 rows per block ----
    const int row = (bid - 768) * 4 + (threadIdx.x >> 6);
    const float4* xr = (const float4*)(x + (size_t)row * C_);
    float s = 0.f, ss = 0.f;
#pragma unroll
    for (int j = 0; j < 4; ++j) {
      float4 vv = xr[lane + 64 * j];
      s += vv.x + vv.y + vv.z + vv.w;
      ss += vv.x * vv.x + vv.y * vv.y + vv.z * vv.z + vv.w * vv.w;
    }
    s = wsumf(s);
    ss = wsumf(ss);
    const float mean = s * (1.f / 1024.f);
    const float var = ss * (1.f / 1024.f) - mean * mean;
    const float theta =
        alpha_p[0] * tanhf(mean) + beta_p[0] * (1.f / (1.f + __expf(-var)));
    if (lane == 0) fac[row] = 1.f + 0.45125f * theta;  // lc = 0.5*0.95^2
  }
}

// ---------- out = attn_out @ w_out + b_out ----------
__global__ __launch_bounds__(256) void gemm_out_kernel(
    const float* __restrict__ a, const float* __restrict__ w,
    const float* __restrict__ bias, float* __restrict__ out) {
  __shared__ unsigned a_hm[128 * KPAD];
  __shared__ unsigned b_hm[64 * KPAD];
  f32x4 acc[4][2];
#pragma unroll
  for (int i = 0; i < 4; ++i)
#pragma unroll
    for (int j = 0; j < 2; ++j) acc[i][j] = (f32x4){0.f, 0.f, 0.f, 0.f};
  const int m0 = blockIdx.y * 128, n0 = blockIdx.x * 64;
  mfma_core3(a, w, C_, C_, m0, n0, a_hm, b_hm, acc);

  const int lane = threadIdx.x & 63;
  const int wro = ((threadIdx.x >> 7) & 1) * 64;
  const int wco = ((threadIdx.x >> 6) & 1) * 32;
  const int rbase = (lane >> 4) * 4, cc = lane & 15;
#pragma unroll
  for (int rt = 0; rt < 4; ++rt) {
    const int m = m0 + wro + rt * 16 + rbase;
#pragma unroll
    for (int ct = 0; ct < 2; ++ct) {
      const int j = n0 + wco + ct * 16 + cc;
      const float bj = bias[j];
      const f32x4 c = acc[rt][ct];
      float* dst = out + (size_t)m * C_ + j;
      dst[0] = c[0] + bj;
      dst[C_] = c[1] + bj;
      dst[2 * C_] = c[2] + bj;
      dst[3 * C_] = c[3] + bj;
    }
  }
}

// ---------- attention: MFMA scores (6-product planes) + round-12 selection ----------
// Block = 4 waves, 16 queries. Wave wid computes keys wid*256..+255 for all 16
// queries into LDS score board S[16][1024] (orderu u32), barrier, then each
// wave runs the verified selection/PV on its 4 queries (key = lane + 64j).
__global__ __launch_bounds__(256) void attn_kernel(
    const ushort_t* __restrict__ qh, const ushort_t* __restrict__ qm,
    const ushort_t* __restrict__ ql, const ushort_t* __restrict__ kh,
    const ushort_t* __restrict__ km, const ushort_t* __restrict__ kl,
    const float* __restrict__ vw, const float* __restrict__ fac,
    float* __restrict__ ao) {
  const int lane = threadIdx.x & 63;
  const int wid = threadIdx.x >> 6;
  const int qblk = blockIdx.x * 16;
  const int bh = qblk >> 10;
  const int b = bh >> 4, h = bh & 15;
  const int qbase = qblk & (N_ - 1);
  const int q0 = qbase + wid * 4;

  __shared__ unsigned S[16 * 1024];  // 64KB score board; sel buffers alias in

  const int fr = lane & 15, fko = (lane >> 4) * 8;

  // ---- A fragments: 16 block queries x 64 d, 3 planes x 2 k-halves ----
  const size_t qoff = (((size_t)bh << 10) + qbase + fr) * 64 + fko;
  short8 A[3][2];
  A[0][0] = *(const short8*)(qh + qoff);
  A[0][1] = *(const short8*)(qh + qoff + 32);
  A[1][0] = *(const short8*)(qm + qoff);
  A[1][1] = *(const short8*)(qm + qoff + 32);
  A[2][0] = *(const short8*)(ql + qoff);
  A[2][1] = *(const short8*)(ql + qoff + 32);

  // ---- score phase: 16 tiles x 12 mfma ----
  for (int t = 0; t < 16; ++t) {
    const int key0 = (wid << 8) + (t << 4);
    const size_t koff = (((size_t)bh << 10) + key0 + fr) * 64 + fko;
    short8 Bf[3][2];
    Bf[0][0] = *(const short8*)(kh + koff);
    Bf[0][1] = *(const short8*)(kh + koff + 32);
    Bf[1][0] = *(const short8*)(km + koff);
    Bf[1][1] = *(const short8*)(km + koff + 32);
    Bf[2][0] = *(const short8*)(kl + koff);
    Bf[2][1] = *(const short8*)(kl + koff + 32);
    f32x4 acc = (f32x4){0.f, 0.f, 0.f, 0.f};
    // products smallest-first: h*l, l*h, m*m, h*m, m*h, h*h (halves 0 then 1)
    acc = __builtin_amdgcn_mfma_f32_16x16x32_bf16(A[0][0], Bf[2][0], acc, 0, 0, 0);
    acc = __builtin_amdgcn_mfma_f32_16x16x32_bf16(A[0][1], Bf[2][1], acc, 0, 0, 0);
    acc = __builtin_amdgcn_mfma_f32_16x16x32_bf16(A[2][0], Bf[0][0], acc, 0, 0, 0);
    acc = __builtin_amdgcn_mfma_f32_16x16x32_bf16(A[2][1], Bf[0][1], acc, 0, 0, 0);
    acc = __builtin_amdgcn_mfma_f32_16x16x32_bf16(A[1][0], Bf[1][0], acc, 0, 0, 0);
    acc = __builtin_amdgcn_mfma_f32_16x16x32_bf16(A[1][1], Bf[1][1], acc, 0, 0, 0);
    acc = __builtin_amdgcn_mfma_f32_16x16x32_bf16(A[0][0], Bf[1][0], acc, 0, 0, 0);
    acc = __builtin_amdgcn_mfma_f32_16x16x32_bf16(A[0][1], Bf[1][1], acc, 0, 0, 0);
    acc = __builtin_amdgcn_mfma_f32_16x16x32_bf16(A[1][0], Bf[0][0], acc, 0, 0, 0);
    acc = __builtin_amdgcn_mfma_f32_16x16x32_bf16(A[1][1], Bf[0][1], acc, 0, 0, 0);
    acc = __builtin_amdgcn_mfma_f32_16x16x32_bf16(A[0][0], Bf[0][0], acc, 0, 0, 0);
    acc = __builtin_amdgcn_mfma_f32_16x16x32_bf16(A[0][1], Bf[0][1], acc, 0, 0, 0);
#pragma unroll
    for (int r = 0; r < 4; ++r) {
      const int qrow = (lane >> 4) * 4 + r;  // C/D: row=(lane>>4)*4+reg
      S[(qrow << 10) + key0 + fr] = orderu((acc[r] * 0.125f) / 0.8f);
    }
  }
  __syncthreads();

  // ---- load selection state u[4][16]; key = lane + 64j ----
  unsigned u[4][16];
#pragma unroll
  for (int qq = 0; qq < 4; ++qq)
#pragma unroll
    for (int j = 0; j < 16; ++j)
      u[qq][j] = S[((wid * 4 + qq) << 10) + lane + (j << 6)];

  // wave-private selection buffers alias into this wave's (now dead) S rows
  unsigned* su_ = S + (wid << 12);
  float* sv_ = (float*)(su_ + 64);
  int* ck_ = (int*)(su_ + 128);
  float* cv_ = (float*)(su_ + 192);

  const unsigned long long ltmask = (1ull << lane) - 1ull;

  unsigned mu[4], l0[4];
#pragma unroll
  for (int q = 0; q < 4; ++q) {
    unsigned mq = u[q][0];
#pragma unroll
    for (int j = 1; j < 16; ++j) mq = max(mq, u[q][j]);
    mu[q] = mq;
    l0[q] = mq;
  }
#pragma unroll
  for (int off = 32; off; off >>= 1) {
#pragma unroll
    for (int q = 0; q < 4; ++q) {
      mu[q] = max(mu[q], (unsigned)__shfl_xor((int)mu[q], off, 64));
      l0[q] = min(l0[q], (unsigned)__shfl_xor((int)l0[q], off, 64));
    }
  }

  unsigned lo[4], hi[4];
#pragma unroll
  for (int q = 0; q < 4; ++q) {
    lo[q] = l0[q];
    hi[q] = mu[q];
  }
  while ((lo[0] < hi[0]) | (lo[1] < hi[1]) | (lo[2] < hi[2]) |
         (lo[3] < hi[3])) {
#pragma unroll
    for (int q = 0; q < 4; ++q) {
      if (lo[q] < hi[q]) {
        const unsigned mid = lo[q] + ((hi[q] - lo[q]) >> 1) + 1u;
        int c = 0;
#pragma unroll
        for (int j = 0; j < 16; ++j)
          c += (int)__popcll(__ballot(u[q][j] >= mid));
        if (c >= 64) lo[q] = mid;
        else hi[q] = mid - 1u;
      }
    }
  }

  const float* vb = vw + ((size_t)bh << 16);
#pragma unroll
  for (int qq = 0; qq < 4; ++qq) {
    const unsigned kthu = lo[qq];
    const float m = iorderu(mu[qq]);

    float e[16];
    float zl = 0.f;
#pragma unroll
    for (int j = 0; j < 16; ++j) {
      const float ej = (u[qq][j] >= kthu) ? __expf(iorderu(u[qq][j]) - m) : 0.f;
      e[j] = ej;
      zl += ej;
    }
    const float Z = wsumf(zl);
    const float limit = 0.9f * Z;

    int base = 0;
#pragma unroll
    for (int j = 0; j < 16; ++j) {
      const bool f = (u[qq][j] >= kthu);
      const unsigned long long mb = __ballot(f);
      if (f) {
        const int pos = base + (int)__popcll(mb & ltmask);
        if (pos < 64) {
          su_[pos] = u[qq][j];
          sv_[pos] = e[j];
        }
      }
      base += (int)__popcll(mb);
    }

    unsigned sk = ~su_[lane];
    float se = sv_[lane];
#pragma unroll
    for (int k = 2; k <= 64; k <<= 1) {
#pragma unroll
      for (int j = k >> 1; j; j >>= 1) {
        const unsigned pk = (unsigned)__shfl_xor((int)sk, j, 64);
        const float pe = __shfl_xor(se, j, 64);
        const bool takeMin = (((lane & j) == 0) == ((lane & k) == 0));
        const bool sw = takeMin ? (pk < sk) : (pk > sk);
        if (sw) {
          sk = pk;
          se = pe;
        }
      }
    }

    float pre = se;
#pragma unroll
    for (int off = 1; off <= 32; off <<= 1) {
      const float t = __shfl_up(pre, off, 64);
      if (lane >= off) pre += t;
    }
    const float excl = pre - se;
    const bool keep = (excl <= limit);
    const unsigned long long km2 = __ballot(keep);
    const int L = 63 - __builtin_clzll(km2);
    const unsigned thr = ~(unsigned)__shfl((int)sk, L, 64);

    float z2l = 0.f;
#pragma unroll
    for (int j = 0; j < 16; ++j) z2l += (u[qq][j] >= thr) ? e[j] : 0.f;
    const float Z2 = wsumf(z2l);
    const float wsc = fac[(b << 10) + q0 + qq] / Z2;

    int M = 0;
#pragma unroll
    for (int j = 0; j < 16; ++j) {
      const bool f = (u[qq][j] >= thr);
      const unsigned long long mb = __ballot(f);
      if (f) {
        const int pos = M + (int)__popcll(mb & ltmask);
        if (pos < 64) {
          ck_[pos] = lane + (j << 6);  // key = lane + 64j
          cv_[pos] = e[j] * wsc;
        }
      }
      M += (int)__popcll(mb);
    }
    if (M > 64) M = 64;

    float a0 = 0.f, a1 = 0.f, a2 = 0.f, a3 = 0.f;
    int i = 0;
    for (; i + 4 <= M; i += 4) {
      const int k0 = ck_[i], k1 = ck_[i + 1];
      const int k2 = ck_[i + 2], k3 = ck_[i + 3];
      const float c0 = cv_[i], c1 = cv_[i + 1];
      const float c2 = cv_[i + 2], c3 = cv_[i + 3];
      a0 = fmaf(c0, vb[((size_t)k0 << 6) + lane], a0);
      a1 = fmaf(c1, vb[((size_t)k1 << 6) + lane], a1);
      a2 = fmaf(c2, vb[((size_t)k2 << 6) + lane], a2);
      a3 = fmaf(c3, vb[((size_t)k3 << 6) + lane], a3);
    }
    for (; i < M; ++i)
      a0 = fmaf(cv_[i], vb[((size_t)ck_[i] << 6) + lane], a0);
    const float o = (a0 + a1) + (a2 + a3);

    ao[(((size_t)b << 10) + q0 + qq) * C_ + (h << 6) + lane] = o;
  }
}

extern "C" void kernel_launch(void* const* d_in, const int* in_sizes, int n_in,
                              void* d_out, int out_size, void* d_ws,
                              size_t ws_size, hipStream_t stream) {
  const float* x = (const float*)d_in[0];
  const float* wqkv = (const float*)d_in[1];
  const float* wout = (const float*)d_in[2];
  const float* bout = (const float*)d_in[3];
  const float* alpha = (const float*)d_in[4];
  const float* beta = (const float*)d_in[5];
  float* out = (float*)d_out;

  float* ws = (float*)d_ws;
  const size_t M1 = 1u << 20;  // 1M floats
  float* vw = ws;              // 2M fl
  float* ao = ws + 2 * M1;     // 2M fl
  float* fc = ws + 4 * M1;     // small (padded 4K)
  ushort_t* pb = (ushort_t*)(ws + 4 * M1 + 4096);
  ushort_t* qh = pb;                 // 2M ushorts per plane
  ushort_t* qm = pb + 2 * M1;
  ushort_t* ql = pb + 4 * M1;
  ushort_t* kh = pb + 6 * M1;
  ushort_t* km = pb + 8 * M1;
  ushort_t* kl = pb + 10 * M1;

  front_kernel<<<1280, 256, 0, stream>>>(x, wqkv, alpha, beta, qh, qm, ql, kh,
                                         km, kl, vw, fc);
  attn_kernel<<<(B_ * H_ * N_) / 16, 256, 0, stream>>>(qh, qm, ql, kh, km, kl,
                                                       vw, fc, ao);
  gemm_out_kernel<<<dim3(16, 16), 256, 0, stream>>>(ao, wout, bout, out);
}

// Round 16
// 376.537 us; speedup vs baseline: 1.2920x; 1.2920x over previous
//
#include <hip/hip_runtime.h>

#define B_ 2
#define N_ 1024
#define C_ 1024
#define H_ 16
#define HD_ 64
#define KPAD 36   // u32 per LDS row (144B stride): 16B-aligned b128 reads
#define KPADL 40  // u16 per LDS row (80B stride): 16B-aligned b128 reads

typedef short short8 __attribute__((ext_vector_type(8)));
typedef float f32x4 __attribute__((ext_vector_type(4)));

union U16 {
  uint4 q;
  unsigned u[4];
  short8 s;
};

// ---------- wave-wide (64-lane) helpers ----------
__device__ __forceinline__ float wsumf(float x) {
#pragma unroll
  for (int off = 32; off; off >>= 1) x += __shfl_xor(x, off, 64);
  return x;
}
__device__ __forceinline__ unsigned orderu(float f) {
  unsigned b = __float_as_uint(f);
  return (b & 0x80000000u) ? ~b : (b | 0x80000000u);
}
__device__ __forceinline__ float iorderu(unsigned x) {
  unsigned b = (x & 0x80000000u) ? (x & 0x7FFFFFFFu) : ~x;
  return __uint_as_float(b);
}

// 2-term split f32 -> packed u32: hi bf16 low16, lo bf16 high16 (RTNE)
__device__ __forceinline__ unsigned splitf2(float f) {
  unsigned u = __float_as_uint(f);
  unsigned t = (u + 0x7fffu + ((u >> 16) & 1u)) & 0xffff0000u;
  float r = f - __uint_as_float(t);  // exact
  unsigned v = __float_as_uint(r);
  unsigned tv = v + 0x7fffu + ((v >> 16) & 1u);
  return (t >> 16) | (tv & 0xffff0000u);
}
// 3-term split: hm = hi|mid packed u32, lo = third bf16 term
__device__ __forceinline__ void splitf3(float f, unsigned& hm,
                                        unsigned short& lo) {
  unsigned u = __float_as_uint(f);
  unsigned t = (u + 0x7fffu + ((u >> 16) & 1u)) & 0xffff0000u;
  float r1 = f - __uint_as_float(t);  // exact
  unsigned v = __float_as_uint(r1);
  unsigned tv = (v + 0x7fffu + ((v >> 16) & 1u)) & 0xffff0000u;
  float r2 = r1 - __uint_as_float(tv);  // exact
  unsigned w = __float_as_uint(r2);
  unsigned tw = w + 0x7fffu + ((w >> 16) & 1u);
  hm = (t >> 16) | tv;
  lo = (unsigned short)(tw >> 16);
}

__device__ __forceinline__ void unpack_hm(const unsigned* p, short8& h,
                                          short8& l) {
  const uint4 X = *(const uint4*)p;
  const uint4 Y = *(const uint4*)(p + 4);
  U16 Hh, Ll;
  Hh.u[0] = (X.x & 0xffffu) | (X.y << 16);
  Hh.u[1] = (X.z & 0xffffu) | (X.w << 16);
  Hh.u[2] = (Y.x & 0xffffu) | (Y.y << 16);
  Hh.u[3] = (Y.z & 0xffffu) | (Y.w << 16);
  Ll.u[0] = (X.x >> 16) | (X.y & 0xffff0000u);
  Ll.u[1] = (X.z >> 16) | (X.w & 0xffff0000u);
  Ll.u[2] = (Y.x >> 16) | (Y.y & 0xffff0000u);
  Ll.u[3] = (Y.z >> 16) | (Y.w & 0xffff0000u);
  h = Hh.s;
  l = Ll.s;
}

// ---------- 3-term split MFMA core, 128x64 tile, BK=32, 4 waves (2x2) ----------
// 6 products {h*l, l*h, m*m, h*m, m*h, h*h}, smallest-first (q/k precision).
__device__ __forceinline__ void mfma_core6(
    const float* __restrict__ A, const float* __restrict__ Bm, int lda,
    int ldb, int m0, int n0, unsigned* a_hm, unsigned* b_hm,
    unsigned short* a_lo, unsigned short* b_lo, f32x4 acc[4][2]) {
  const int tid = threadIdx.x;
  const int lane = tid & 63;
  const int wro = ((tid >> 7) & 1) * 64;  // wave row offset (0/64)
  const int wco = ((tid >> 6) & 1) * 32;  // wave col offset (0/32)
  const int a_k4 = (tid & 7) * 4, a_m = tid >> 3;  // A rows a_m+32j
  const int b_k = tid >> 4;                        // B k-rows b_k, b_k+16
  const int b_j4 = (tid & 15) * 4;                 // B col chunk
  const int fr = lane & 15, fk = (lane >> 4) * 8;

  float4 aR[4], bR[2];
#pragma unroll
  for (int j = 0; j < 4; ++j)
    aR[j] = *(const float4*)(A + (size_t)(m0 + a_m + 32 * j) * lda + a_k4);
  bR[0] = *(const float4*)(Bm + (size_t)b_k * ldb + n0 + b_j4);
  bR[1] = *(const float4*)(Bm + (size_t)(b_k + 16) * ldb + n0 + b_j4);

  for (int kt = 0; kt < 32; ++kt) {
    __syncthreads();  // prior iteration's frag reads done
#pragma unroll
    for (int j = 0; j < 4; ++j) {
      uint4 w;
      ushort4 l;
      splitf3(aR[j].x, w.x, l.x);
      splitf3(aR[j].y, w.y, l.y);
      splitf3(aR[j].z, w.z, l.z);
      splitf3(aR[j].w, w.w, l.w);
      *(uint4*)(a_hm + (a_m + 32 * j) * KPAD + a_k4) = w;
      *(ushort4*)(a_lo + (a_m + 32 * j) * KPADL + a_k4) = l;
    }
    {
      unsigned hm;
      unsigned short lo;
      splitf3(bR[0].x, hm, lo);
      b_hm[(b_j4 + 0) * KPAD + b_k] = hm;
      b_lo[(b_j4 + 0) * KPADL + b_k] = lo;
      splitf3(bR[0].y, hm, lo);
      b_hm[(b_j4 + 1) * KPAD + b_k] = hm;
      b_lo[(b_j4 + 1) * KPADL + b_k] = lo;
      splitf3(bR[0].z, hm, lo);
      b_hm[(b_j4 + 2) * KPAD + b_k] = hm;
      b_lo[(b_j4 + 2) * KPADL + b_k] = lo;
      splitf3(bR[0].w, hm, lo);
      b_hm[(b_j4 + 3) * KPAD + b_k] = hm;
      b_lo[(b_j4 + 3) * KPADL + b_k] = lo;
      splitf3(bR[1].x, hm, lo);
      b_hm[(b_j4 + 0) * KPAD + b_k + 16] = hm;
      b_lo[(b_j4 + 0) * KPADL + b_k + 16] = lo;
      splitf3(bR[1].y, hm, lo);
      b_hm[(b_j4 + 1) * KPAD + b_k + 16] = hm;
      b_lo[(b_j4 + 1) * KPADL + b_k + 16] = lo;
      splitf3(bR[1].z, hm, lo);
      b_hm[(b_j4 + 2) * KPAD + b_k + 16] = hm;
      b_lo[(b_j4 + 2) * KPADL + b_k + 16] = lo;
      splitf3(bR[1].w, hm, lo);
      b_hm[(b_j4 + 3) * KPAD + b_k + 16] = hm;
      b_lo[(b_j4 + 3) * KPADL + b_k + 16] = lo;
    }
    __syncthreads();
    if (kt + 1 < 32) {  // prefetch next k-tile; hides under MFMA
      const int kb = (kt + 1) * 32;
#pragma unroll
      for (int j = 0; j < 4; ++j)
        aR[j] =
            *(const float4*)(A + (size_t)(m0 + a_m + 32 * j) * lda + kb + a_k4);
      bR[0] = *(const float4*)(Bm + (size_t)(kb + b_k) * ldb + n0 + b_j4);
      bR[1] = *(const float4*)(Bm + (size_t)(kb + b_k + 16) * ldb + n0 + b_j4);
    }
    short8 ah[4], am[4], al[4];
#pragma unroll
    for (int rt = 0; rt < 4; ++rt) {
      const int row = wro + rt * 16 + fr;
      unpack_hm(a_hm + row * KPAD + fk, ah[rt], am[rt]);
      U16 L;
      L.q = *(const uint4*)(a_lo + row * KPADL + fk);
      al[rt] = L.s;
    }
#pragma unroll
    for (int ct = 0; ct < 2; ++ct) {
      const int row = wco + ct * 16 + fr;
      short8 bh, bm, bl;
      unpack_hm(b_hm + row * KPAD + fk, bh, bm);
      U16 L;
      L.q = *(const uint4*)(b_lo + row * KPADL + fk);
      bl = L.s;
#pragma unroll
      for (int rt = 0; rt < 4; ++rt) {
        f32x4 c = acc[rt][ct];
        c = __builtin_amdgcn_mfma_f32_16x16x32_bf16(ah[rt], bl, c, 0, 0, 0);
        c = __builtin_amdgcn_mfma_f32_16x16x32_bf16(al[rt], bh, c, 0, 0, 0);
        c = __builtin_amdgcn_mfma_f32_16x16x32_bf16(am[rt], bm, c, 0, 0, 0);
        c = __builtin_amdgcn_mfma_f32_16x16x32_bf16(ah[rt], bm, c, 0, 0, 0);
        c = __builtin_amdgcn_mfma_f32_16x16x32_bf16(am[rt], bh, c, 0, 0, 0);
        c = __builtin_amdgcn_mfma_f32_16x16x32_bf16(ah[rt], bh, c, 0, 0, 0);
        acc[rt][ct] = c;
      }
    }
  }
}

// ---------- 2-term split MFMA core, 128x64 tile (v / out-proj) ----------
// 3 products {h*l, l*h, h*h}, smallest-first.
__device__ __forceinline__ void mfma_core3(const float* __restrict__ A,
                                           const float* __restrict__ Bm,
                                           int lda, int ldb, int m0, int n0,
                                           unsigned* a_hm, unsigned* b_hm,
                                           f32x4 acc[4][2]) {
  const int tid = threadIdx.x;
  const int lane = tid & 63;
  const int wro = ((tid >> 7) & 1) * 64;
  const int wco = ((tid >> 6) & 1) * 32;
  const int a_k4 = (tid & 7) * 4, a_m = tid >> 3;
  const int b_k = tid >> 4;
  const int b_j4 = (tid & 15) * 4;
  const int fr = lane & 15, fk = (lane >> 4) * 8;

  float4 aR[4], bR[2];
#pragma unroll
  for (int j = 0; j < 4; ++j)
    aR[j] = *(const float4*)(A + (size_t)(m0 + a_m + 32 * j) * lda + a_k4);
  bR[0] = *(const float4*)(Bm + (size_t)b_k * ldb + n0 + b_j4);
  bR[1] = *(const float4*)(Bm + (size_t)(b_k + 16) * ldb + n0 + b_j4);

  for (int kt = 0; kt < 32; ++kt) {
    __syncthreads();
#pragma unroll
    for (int j = 0; j < 4; ++j) {
      uint4 w;
      w.x = splitf2(aR[j].x);
      w.y = splitf2(aR[j].y);
      w.z = splitf2(aR[j].z);
      w.w = splitf2(aR[j].w);
      *(uint4*)(a_hm + (a_m + 32 * j) * KPAD + a_k4) = w;
    }
    {
      b_hm[(b_j4 + 0) * KPAD + b_k] = splitf2(bR[0].x);
      b_hm[(b_j4 + 1) * KPAD + b_k] = splitf2(bR[0].y);
      b_hm[(b_j4 + 2) * KPAD + b_k] = splitf2(bR[0].z);
      b_hm[(b_j4 + 3) * KPAD + b_k] = splitf2(bR[0].w);
      b_hm[(b_j4 + 0) * KPAD + b_k + 16] = splitf2(bR[1].x);
      b_hm[(b_j4 + 1) * KPAD + b_k + 16] = splitf2(bR[1].y);
      b_hm[(b_j4 + 2) * KPAD + b_k + 16] = splitf2(bR[1].z);
      b_hm[(b_j4 + 3) * KPAD + b_k + 16] = splitf2(bR[1].w);
    }
    __syncthreads();
    if (kt + 1 < 32) {
      const int kb = (kt + 1) * 32;
#pragma unroll
      for (int j = 0; j < 4; ++j)
        aR[j] =
            *(const float4*)(A + (size_t)(m0 + a_m + 32 * j) * lda + kb + a_k4);
      bR[0] = *(const float4*)(Bm + (size_t)(kb + b_k) * ldb + n0 + b_j4);
      bR[1] = *(const float4*)(Bm + (size_t)(kb + b_k + 16) * ldb + n0 + b_j4);
    }
    short8 ah[4], al[4];
#pragma unroll
    for (int rt = 0; rt < 4; ++rt)
      unpack_hm(a_hm + (wro + rt * 16 + fr) * KPAD + fk, ah[rt], al[rt]);
#pragma unroll
    for (int ct = 0; ct < 2; ++ct) {
      short8 bh, bl;
      unpack_hm(b_hm + (wco + ct * 16 + fr) * KPAD + fk, bh, bl);
#pragma unroll
      for (int rt = 0; rt < 4; ++rt) {
        f32x4 c = acc[rt][ct];
        c = __builtin_amdgcn_mfma_f32_16x16x32_bf16(ah[rt], bl, c, 0, 0, 0);
        c = __builtin_amdgcn_mfma_f32_16x16x32_bf16(al[rt], bh, c, 0, 0, 0);
        c = __builtin_amdgcn_mfma_f32_16x16x32_bf16(ah[rt], bh, c, 0, 0, 0);
        acc[rt][ct] = c;
      }
    }
  }
}

// ---------- fused front: qk tiles (0..511) + v tiles (512..767) +
//            NKAT factor groups (768..1279), one dispatch ----------
__global__ __launch_bounds__(256) void front_kernel(
    const float* __restrict__ x, const float* __restrict__ w,
    const float* __restrict__ alpha_p, const float* __restrict__ beta_p,
    float* __restrict__ q, float* __restrict__ ktb, float* __restrict__ v,
    float* __restrict__ fac) {
  __shared__ unsigned a_hm[128 * KPAD];
  __shared__ unsigned b_hm[64 * KPAD];
  __shared__ unsigned short a_lo[128 * KPADL];
  __shared__ unsigned short b_lo[64 * KPADL];

  const int bid = blockIdx.x;
  const int lane = threadIdx.x & 63;

  if (bid < 512) {  // ---- qk tile (6-product, 3-term split) ----
    f32x4 acc[4][2];
#pragma unroll
    for (int i = 0; i < 4; ++i)
#pragma unroll
      for (int j = 0; j < 2; ++j) acc[i][j] = (f32x4){0.f, 0.f, 0.f, 0.f};
    const int m0 = (bid >> 5) * 128, n0 = (bid & 31) * 64;
    mfma_core6(x, w, C_, 3 * C_, m0, n0, a_hm, b_hm, a_lo, b_lo, acc);

    const int wro = ((threadIdx.x >> 7) & 1) * 64;
    const int wco = ((threadIdx.x >> 6) & 1) * 32;
    const int rbase = (lane >> 4) * 4, cc = lane & 15;
#pragma unroll
    for (int rt = 0; rt < 4; ++rt) {
      const int m = m0 + wro + rt * 16 + rbase;
      const int bb2 = m >> 10, nn = m & 1023;
#pragma unroll
      for (int ct = 0; ct < 2; ++ct) {
        const int j = n0 + wco + ct * 16 + cc;
        const int sel = j >> 10, hh = (j >> 6) & 15, d0 = j & 63;
        const f32x4 c = acc[rt][ct];
        if (sel == 1) {  // K transposed: contiguous along token index nn
          *(float4*)(ktb + (((size_t)(bb2 * 16 + hh) * HD_ + d0) << 10) + nn) =
              make_float4(c[0], c[1], c[2], c[3]);
        } else {
          float* dst = q + (((size_t)(bb2 * 16 + hh) << 10) + nn) * HD_ + d0;
          dst[0] = c[0];
          dst[HD_] = c[1];
          dst[2 * HD_] = c[2];
          dst[3 * HD_] = c[3];
        }
      }
    }
  } else if (bid < 768) {  // ---- v tile (3-product, 2-term split) ----
    f32x4 acc[4][2];
#pragma unroll
    for (int i = 0; i < 4; ++i)
#pragma unroll
      for (int j = 0; j < 2; ++j) acc[i][j] = (f32x4){0.f, 0.f, 0.f, 0.f};
    const int vb = bid - 512;
    const int m0 = (vb >> 4) * 128, n0 = 2048 + (vb & 15) * 64;
    mfma_core3(x, w, C_, 3 * C_, m0, n0, a_hm, b_hm, acc);

    const int wro = ((threadIdx.x >> 7) & 1) * 64;
    const int wco = ((threadIdx.x >> 6) & 1) * 32;
    const int rbase = (lane >> 4) * 4, cc = lane & 15;
#pragma unroll
    for (int rt = 0; rt < 4; ++rt) {
      const int m = m0 + wro + rt * 16 + rbase;
      const int bb = m >> 10, nn = m & 1023;
#pragma unroll
      for (int ct = 0; ct < 2; ++ct) {
        const int jv = (n0 - 2048) + wco + ct * 16 + cc;
        const int hh = (jv >> 6) & 15, d0 = jv & 63;
        const f32x4 c = acc[rt][ct];
        float* dst = v + (((size_t)(bb * 16 + hh) << 10) + nn) * HD_ + d0;
        dst[0] = c[0];
        dst[HD_] = c[1];
        dst[2 * HD_] = c[2];
        dst[3 * HD_] = c[3];
      }
    }
  } else {  // ---- NKAT factor: 4 rows per block (one per wave) ----
    const int row = (bid - 768) * 4 + (threadIdx.x >> 6);
    const float4* xr = (const float4*)(x + (size_t)row * C_);
    float s = 0.f, ss = 0.f;
#pragma unroll
    for (int j = 0; j < 4; ++j) {
      float4 vv = xr[lane + 64 * j];
      s += vv.x + vv.y + vv.z + vv.w;
      ss += vv.x * vv.x + vv.y * vv.y + vv.z * vv.z + vv.w * vv.w;
    }
    s = wsumf(s);
    ss = wsumf(ss);
    const float mean = s * (1.f / 1024.f);
    const float var = ss * (1.f / 1024.f) - mean * mean;
    const float theta =
        alpha_p[0] * tanhf(mean) + beta_p[0] * (1.f / (1.f + __expf(-var)));
    if (lane == 0) fac[row] = 1.f + 0.45125f * theta;  // lc = 0.5*0.95^2
  }
}

// ---------- out = attn_out @ w_out + b_out ----------
__global__ __launch_bounds__(256) void gemm_out_kernel(
    const float* __restrict__ a, const float* __restrict__ w,
    const float* __restrict__ bias, float* __restrict__ out) {
  __shared__ unsigned a_hm[128 * KPAD];
  __shared__ unsigned b_hm[64 * KPAD];
  f32x4 acc[4][2];
#pragma unroll
  for (int i = 0; i < 4; ++i)
#pragma unroll
    for (int j = 0; j < 2; ++j) acc[i][j] = (f32x4){0.f, 0.f, 0.f, 0.f};
  const int m0 = blockIdx.y * 128, n0 = blockIdx.x * 64;
  mfma_core3(a, w, C_, C_, m0, n0, a_hm, b_hm, acc);

  const int lane = threadIdx.x & 63;
  const int wro = ((threadIdx.x >> 7) & 1) * 64;
  const int wco = ((threadIdx.x >> 6) & 1) * 32;
  const int rbase = (lane >> 4) * 4, cc = lane & 15;
#pragma unroll
  for (int rt = 0; rt < 4; ++rt) {
    const int m = m0 + wro + rt * 16 + rbase;
#pragma unroll
    for (int ct = 0; ct < 2; ++ct) {
      const int j = n0 + wco + ct * 16 + cc;
      const float bj = bias[j];
      const f32x4 c = acc[rt][ct];
      float* dst = out + (size_t)m * C_ + j;
      dst[0] = c[0] + bj;
      dst[C_] = c[1] + bj;
      dst[2 * C_] = c[2] + bj;
      dst[3 * C_] = c[3] + bj;
    }
  }
}

// ---------- attention: round-12 kernel, unchanged (verified) ----------
__global__ __launch_bounds__(256) void attn_kernel(
    const float* __restrict__ qw, const float* __restrict__ kt,
    const float* __restrict__ vw, const float* __restrict__ fac,
    float* __restrict__ ao) {
  const int lane = threadIdx.x & 63;
  const int wid = threadIdx.x >> 6;
  const int qblk = blockIdx.x * 16;
  const int bh = qblk >> 10;
  const int b = bh >> 4, h = bh & 15;
  const int q0 = (qblk & (N_ - 1)) + wid * 4;

  __shared__ __align__(16) float q_ldsT[4][HD_][4];
  __shared__ unsigned su[4][64];
  __shared__ float sv[4][64];
  __shared__ int ck[4][64];
  __shared__ float cv[4][64];

  {
    const int qq = lane >> 4, dp = (lane & 15) << 2;
    const float4 v =
        *(const float4*)(qw + ((size_t)bh * N_ + q0 + qq) * HD_ + dp);
    q_ldsT[wid][dp + 0][qq] = v.x;
    q_ldsT[wid][dp + 1][qq] = v.y;
    q_ldsT[wid][dp + 2][qq] = v.z;
    q_ldsT[wid][dp + 3][qq] = v.w;
  }

  const float* ktb = kt + ((size_t)bh * HD_ * N_);
  const unsigned long long ltmask = (1ull << lane) - 1ull;
  unsigned u[4][16];

  for (int pass = 0; pass < 4; ++pass) {
    float acc[4][4];
#pragma unroll
    for (int a = 0; a < 4; ++a)
#pragma unroll
      for (int c = 0; c < 4; ++c) acc[a][c] = 0.f;
    const float* kp = ktb + (pass << 8) + (lane << 2);
#pragma unroll 4
    for (int d = 0; d < HD_; ++d) {
      const float4 kv = *(const float4*)(kp + (size_t)d * N_);
      const float4 qv = *(const float4*)(&q_ldsT[wid][d][0]);
      acc[0][0] = fmaf(kv.x, qv.x, acc[0][0]);
      acc[0][1] = fmaf(kv.x, qv.y, acc[0][1]);
      acc[0][2] = fmaf(kv.x, qv.z, acc[0][2]);
      acc[0][3] = fmaf(kv.x, qv.w, acc[0][3]);
      acc[1][0] = fmaf(kv.y, qv.x, acc[1][0]);
      acc[1][1] = fmaf(kv.y, qv.y, acc[1][1]);
      acc[1][2] = fmaf(kv.y, qv.z, acc[1][2]);
      acc[1][3] = fmaf(kv.y, qv.w, acc[1][3]);
      acc[2][0] = fmaf(kv.z, qv.x, acc[2][0]);
      acc[2][1] = fmaf(kv.z, qv.y, acc[2][1]);
      acc[2][2] = fmaf(kv.z, qv.z, acc[2][2]);
      acc[2][3] = fmaf(kv.z, qv.w, acc[2][3]);
      acc[3][0] = fmaf(kv.w, qv.x, acc[3][0]);
      acc[3][1] = fmaf(kv.w, qv.y, acc[3][1]);
      acc[3][2] = fmaf(kv.w, qv.z, acc[3][2]);
      acc[3][3] = fmaf(kv.w, qv.w, acc[3][3]);
    }
#pragma unroll
    for (int jl = 0; jl < 4; ++jl)
#pragma unroll
      for (int q = 0; q < 4; ++q)
        u[q][(pass << 2) + jl] = orderu((acc[jl][q] * 0.125f) / 0.8f);
  }

  unsigned mu[4], l0[4];
#pragma unroll
  for (int q = 0; q < 4; ++q) {
    unsigned mq = u[q][0];
#pragma unroll
    for (int j = 1; j < 16; ++j) mq = max(mq, u[q][j]);
    mu[q] = mq;
    l0[q] = mq;
  }
#pragma unroll
  for (int off = 32; off; off >>= 1) {
#pragma unroll
    for (int q = 0; q < 4; ++q) {
      mu[q] = max(mu[q], (unsigned)__shfl_xor((int)mu[q], off, 64));
      l0[q] = min(l0[q], (unsigned)__shfl_xor((int)l0[q], off, 64));
    }
  }

  unsigned lo[4], hi[4];
#pragma unroll
  for (int q = 0; q < 4; ++q) {
    lo[q] = l0[q];
    hi[q] = mu[q];
  }
  while ((lo[0] < hi[0]) | (lo[1] < hi[1]) | (lo[2] < hi[2]) |
         (lo[3] < hi[3])) {
#pragma unroll
    for (int q = 0; q < 4; ++q) {
      if (lo[q] < hi[q]) {
        const unsigned mid = lo[q] + ((hi[q] - lo[q]) >> 1) + 1u;
        int c = 0;
#pragma unroll
        for (int j = 0; j < 16; ++j)
          c += (int)__popcll(__ballot(u[q][j] >= mid));
        if (c >= 64) lo[q] = mid;
        else hi[q] = mid - 1u;
      }
    }
  }

  const float* vb = vw + ((size_t)bh << 16);
#pragma unroll
  for (int qq = 0; qq < 4; ++qq) {
    const unsigned kthu = lo[qq];
    const float m = iorderu(mu[qq]);

    float e[16];
    float zl = 0.f;
#pragma unroll
    for (int j = 0; j < 16; ++j) {
      const float ej = (u[qq][j] >= kthu) ? __expf(iorderu(u[qq][j]) - m) : 0.f;
      e[j] = ej;
      zl += ej;
    }
    const float Z = wsumf(zl);
    const float limit = 0.9f * Z;

    int base = 0;
#pragma unroll
    for (int j = 0; j < 16; ++j) {
      const bool f = (u[qq][j] >= kthu);
      const unsigned long long mb = __ballot(f);
      if (f) {
        const int pos = base + (int)__popcll(mb & ltmask);
        if (pos < 64) {
          su[wid][pos] = u[qq][j];
          sv[wid][pos] = e[j];
        }
      }
      base += (int)__popcll(mb);
    }

    unsigned sk = ~su[wid][lane];
    float se = sv[wid][lane];
#pragma unroll
    for (int k = 2; k <= 64; k <<= 1) {
#pragma unroll
      for (int j = k >> 1; j; j >>= 1) {
        const unsigned pk = (unsigned)__shfl_xor((int)sk, j, 64);
        const float pe = __shfl_xor(se, j, 64);
        const bool takeMin = (((lane & j) == 0) == ((lane & k) == 0));
        const bool sw = takeMin ? (pk < sk) : (pk > sk);
        if (sw) {
          sk = pk;
          se = pe;
        }
      }
    }

    float pre = se;
#pragma unroll
    for (int off = 1; off <= 32; off <<= 1) {
      const float t = __shfl_up(pre, off, 64);
      if (lane >= off) pre += t;
    }
    const float excl = pre - se;
    const bool keep = (excl <= limit);
    const unsigned long long km = __ballot(keep);
    const int L = 63 - __builtin_clzll(km);
    const unsigned thr = ~(unsigned)__shfl((int)sk, L, 64);

    float z2l = 0.f;
#pragma unroll
    for (int j = 0; j < 16; ++j) z2l += (u[qq][j] >= thr) ? e[j] : 0.f;
    const float Z2 = wsumf(z2l);
    const float wsc = fac[(b << 10) + q0 + qq] / Z2;

    int M = 0;
#pragma unroll
    for (int j = 0; j < 16; ++j) {
      const bool f = (u[qq][j] >= thr);
      const unsigned long long mb = __ballot(f);
      if (f) {
        const int pos = M + (int)__popcll(mb & ltmask);
        if (pos < 64) {
          ck[wid][pos] = ((j >> 2) << 8) + (lane << 2) + (j & 3);
          cv[wid][pos] = e[j] * wsc;
        }
      }
      M += (int)__popcll(mb);
    }
    if (M > 64) M = 64;

    float a0 = 0.f, a1 = 0.f, a2 = 0.f, a3 = 0.f;
    int i = 0;
    for (; i + 4 <= M; i += 4) {
      const int k0 = ck[wid][i], k1 = ck[wid][i + 1];
      const int k2 = ck[wid][i + 2], k3 = ck[wid][i + 3];
      const float c0 = cv[wid][i], c1 = cv[wid][i + 1];
      const float c2 = cv[wid][i + 2], c3 = cv[wid][i + 3];
      a0 = fmaf(c0, vb[((size_t)k0 << 6) + lane], a0);
      a1 = fmaf(c1, vb[((size_t)k1 << 6) + lane], a1);
      a2 = fmaf(c2, vb[((size_t)k2 << 6) + lane], a2);
      a3 = fmaf(c3, vb[((size_t)k3 << 6) + lane], a3);
    }
    for (; i < M; ++i)
      a0 = fmaf(cv[wid][i], vb[((size_t)ck[wid][i] << 6) + lane], a0);
    const float o = (a0 + a1) + (a2 + a3);

    ao[(((size_t)b << 10) + q0 + qq) * C_ + (h << 6) + lane] = o;
  }
}

extern "C" void kernel_launch(void* const* d_in, const int* in_sizes, int n_in,
                              void* d_out, int out_size, void* d_ws,
                              size_t ws_size, hipStream_t stream) {
  const float* x = (const float*)d_in[0];
  const float* wqkv = (const float*)d_in[1];
  const float* wout = (const float*)d_in[2];
  const float* bout = (const float*)d_in[3];
  const float* alpha = (const float*)d_in[4];
  const float* beta = (const float*)d_in[5];
  float* out = (float*)d_out;

  float* ws = (float*)d_ws;
  const size_t SZ = (size_t)B_ * H_ * N_ * HD_;  // 2M floats
  float* qw = ws;
  float* kt = ws + SZ;  // K transposed per head: [bh][d][n]
  float* vw = ws + 2 * SZ;
  float* ao = ws + 3 * SZ;
  float* fc = ws + 4 * SZ;

  front_kernel<<<1280, 256, 0, stream>>>(x, wqkv, alpha, beta, qw, kt, vw, fc);
  attn_kernel<<<(B_ * H_ * N_) / 16, 256, 0, stream>>>(qw, kt, vw, fc, ao);
  gemm_out_kernel<<<dim3(16, 16), 256, 0, stream>>>(ao, wout, bout, out);
}